// Round 15
// baseline (590.314 us; speedup 1.0000x reference)
//
#include <hip/hip_runtime.h>

#define NUM_E 100000
#define NUM_M 200000
#define DIM   128
#define HID   256
#define NG    64
#define TITER 3
#define NB_SCAN 98   // ceil(NUM_E/1024)
#define TM    64     // msg rows per tile (R21-proven)

typedef __attribute__((ext_vector_type(8))) short bf16x8;
typedef __attribute__((ext_vector_type(4))) float f32x4;

__device__ __forceinline__ unsigned short f2bf(float f) {
  unsigned u = __float_as_uint(f);
  u += 0x7FFF + ((u >> 16) & 1);          // RNE
  return (unsigned short)(u >> 16);
}
__device__ __forceinline__ float bf2f(unsigned short h) {
  return __uint_as_float(((unsigned)h) << 16);
}
__device__ __forceinline__ float sigmoidf_(float v) {
  return 1.f / (1.f + __expf(-v));
}
__device__ __forceinline__ float tanhf_(float u) {
  u = fminf(fmaxf(u, -15.f), 15.f);
  float ex = __expf(-2.f * u);
  return (1.f - ex) / (1.f + ex);
}
__device__ __forceinline__ float relu_(float v) { return fmaxf(v, 0.f); }

__device__ __forceinline__ void acc8(float* xs, bf16x8 v) {
  #pragma unroll
  for (int j = 0; j < 8; ++j) xs[j] += bf2f((unsigned short)v[j]);
}

// T2 XOR-swizzle (R20; neutral-to-positive, removes pad).
__device__ __forceinline__ int swzm(int row, int col) {   // msg: 256-ushort rows
  return row * 256 + (col ^ ((row & 7) << 3));
}
__device__ __forceinline__ int swzg(int row, int col) {   // gru: 128-ushort rows
  return row * 128 + (col ^ ((row & 7) << 3));
}

#define MFMA(a, b, c) __builtin_amdgcn_mfma_f32_16x16x32_bf16((a), (b), (c), 0, 0, 0)

// ---------------- 3-kernel parallel scan (coalesced; R10-proven) ----------------
__global__ __launch_bounds__(256) void scan1_kernel(const int* __restrict__ counts,
                                                    int* __restrict__ partials) {
  __shared__ int sh[256];
  int b = blockIdx.x, t = threadIdx.x;
  int i0 = b * 1024 + t * 4;
  int c0 = (i0 + 0 < NUM_E) ? counts[i0 + 0] : 0;
  int c1 = (i0 + 1 < NUM_E) ? counts[i0 + 1] : 0;
  int c2 = (i0 + 2 < NUM_E) ? counts[i0 + 2] : 0;
  int c3 = (i0 + 3 < NUM_E) ? counts[i0 + 3] : 0;
  int tsum = c0 + c1 + c2 + c3;
  sh[t] = tsum;
  __syncthreads();
  for (int off = 1; off < 256; off <<= 1) {
    int v = (t >= off) ? sh[t - off] : 0;
    __syncthreads();
    sh[t] += v;
    __syncthreads();
  }
  if (t == 255) partials[b] = sh[255];
}

__global__ void scan2_kernel(const int* __restrict__ partials, int* __restrict__ base,
                             int* __restrict__ rowptr) {
  if (threadIdx.x == 0) {
    int run = 0;
    for (int b = 0; b < NB_SCAN; ++b) { base[b] = run; run += partials[b]; }
    rowptr[NUM_E] = NUM_M;
  }
}

__global__ __launch_bounds__(256) void scan3_kernel(const int* __restrict__ counts,
                                                    const int* __restrict__ base,
                                                    int* __restrict__ rowptr) {
  __shared__ int sh[256];
  int b = blockIdx.x, t = threadIdx.x;
  int i0 = b * 1024 + t * 4;
  int c0 = (i0 + 0 < NUM_E) ? counts[i0 + 0] : 0;
  int c1 = (i0 + 1 < NUM_E) ? counts[i0 + 1] : 0;
  int c2 = (i0 + 2 < NUM_E) ? counts[i0 + 2] : 0;
  int c3 = (i0 + 3 < NUM_E) ? counts[i0 + 3] : 0;
  int tsum = c0 + c1 + c2 + c3;
  sh[t] = tsum;
  __syncthreads();
  for (int off = 1; off < 256; off <<= 1) {
    int v = (t >= off) ? sh[t - off] : 0;
    __syncthreads();
    sh[t] += v;
    __syncthreads();
  }
  int p = base[b] + (sh[t] - tsum);
  if (i0 + 0 < NUM_E) rowptr[i0 + 0] = p;
  if (i0 + 1 < NUM_E) rowptr[i0 + 1] = p + c0;
  if (i0 + 2 < NUM_E) rowptr[i0 + 2] = p + c0 + c1;
  if (i0 + 3 < NUM_E) rowptr[i0 + 3] = p + c0 + c1 + c2;
}

// ---------------- scatter: writes PACKED (first,second) pairs (R26) ----------------
// msg no longer chases order->first/second (8 random 4B L2 reads/thread/tile);
// it reads fs[] coalesced instead. Same rowptr guard (rocprof replay safety).
__global__ void scatter_kernel(const int* __restrict__ first,
                               const int* __restrict__ second,
                               const int* __restrict__ rowptr,
                               int* __restrict__ cursor, int2* __restrict__ fs) {
  int m = blockIdx.x * blockDim.x + threadIdx.x;
  if (m < NUM_M) {
    int e = second[m];
    int pos = atomicAdd(&cursor[e], 1);
    int idx = rowptr[e] + pos;
    if (idx < rowptr[e + 1]) fs[idx] = make_int2(first[m], e);
  }
}

// ---------------- fused prep: bf16 cvt + weight packs + HIST ----------------
__device__ __forceinline__ void pack_range(
    const float* __restrict__ srcA, const float* __restrict__ srcB, int KrowsA,
    int N, int src_ld, int col_off, unsigned short* __restrict__ dst, int idx) {
  int l = idx & 63;
  int t = idx >> 6;
  int NF = N / 16;
  int nf = t % NF;
  int ks = t / NF;
  int n = nf * 16 + (l & 15) + col_off;
  int k0 = ks * 32 + (l >> 4) * 8;
  unsigned short o[8];
  #pragma unroll
  for (int j = 0; j < 8; ++j) {
    int k = k0 + j;
    const float* src = (k < KrowsA) ? (srcA + (size_t)k * src_ld)
                                    : (srcB + (size_t)(k - KrowsA) * src_ld);
    o[j] = f2bf(src[n]);
  }
  ushort4* d = (ushort4*)(dst + (size_t)idx * 8);
  d[0] = make_ushort4(o[0], o[1], o[2], o[3]);
  d[1] = make_ushort4(o[4], o[5], o[6], o[7]);
}

// grid covers n4 = NUM_E*DIM/4 threads; first NUM_M also do the CSR histogram
// (counts memset'd BEFORE this launch); ids < 24576 also pack weights.
__global__ __launch_bounds__(256) void prep_kernel(
    const float4* __restrict__ ls4, ushort4* __restrict__ lsb4, int n4,
    const int* __restrict__ second, int* __restrict__ counts,
    const float* __restrict__ mW1, const float* __restrict__ mW2,
    const float* __restrict__ gk,  const float* __restrict__ gr,
    unsigned short* __restrict__ W1p,  unsigned short* __restrict__ W2p,
    unsigned short* __restrict__ Wzrp, unsigned short* __restrict__ Wkhp,
    unsigned short* __restrict__ Wrhp) {
  int i = blockIdx.x * 256 + threadIdx.x;
  if (i < n4) {
    float4 v = ls4[i];
    ushort4 o;
    o.x = f2bf(v.x); o.y = f2bf(v.y); o.z = f2bf(v.z); o.w = f2bf(v.w);
    lsb4[i] = o;
  }
  if (i < NUM_M) atomicAdd(&counts[second[i]], 1);
  if      (i < 8192)  pack_range(mW1, mW1, 256, 256, 256, 0,   W1p,  i);
  else if (i < 12288) pack_range(mW2, mW2, 256, 128, 128, 0,   W2p,  i - 8192);
  else if (i < 20480) pack_range(gk,  gr,  128, 256, 384, 0,   Wzrp, i - 12288);
  else if (i < 22528) pack_range(gk,  gk,  128, 128, 384, 256, Wkhp, i - 20480);
  else if (i < 24576) pack_range(gr,  gr,  128, 128, 384, 256, Wrhp, i - 22528);
}

// ---------------- message MLP: 64-row tiles + packed fs reads (R26) ----------------
// R21/R23 structure unchanged; index chain shortened: fs[t+2] (coalesced 8B)
// replaces order[t+2] -> first/second[t+2] (coalesced 4B + 8 random 4B).
__global__ __launch_bounds__(512, 2) void msg_kernel(
    const unsigned short* __restrict__ lsb,   // [E,128] bf16
    const int2* __restrict__ fs,              // [M] packed (first,second), CSR order
    const unsigned short* __restrict__ W1p,   // packed [8 ks][16 nf][64][8]
    const float* __restrict__ b1,
    const unsigned short* __restrict__ W2p,   // packed [8 ks][8 nf][64][8]
    const float* __restrict__ b2,
    unsigned short* __restrict__ msgout)
{
  __shared__ unsigned short actL[2][TM * 256];   // 2 x 32 KB, swizzled
  __shared__ unsigned short h1s[2][TM * 256];    // 2 x 32 KB, swizzled

  const int tid  = threadIdx.x;
  const int wave = tid >> 6;                 // 0..7
  const int lane = tid & 63;
  const int c    = lane & 15;
  const int quad = lane >> 4;

  const int sr  = tid >> 5;                  // 0..15
  const int shf = (tid >> 4) & 1;            // 0 = main(first), 1 = neigh(second)
  const int si  = tid & 15;                  // 16B chunk index

  const bf16x8* W1f = (const bf16x8*)W1p;
  const bf16x8* W2f = (const bf16x8*)W2p;
  bf16x8 w1r[16];                            // 64 VGPR
  #pragma unroll
  for (int ks = 0; ks < 8; ++ks)
    #pragma unroll
    for (int i = 0; i < 2; ++i)
      w1r[ks * 2 + i] = W1f[(ks * 16 + wave * 2 + i) * 64 + lane];
  bf16x8 w2r[8];                             // 32 VGPR
  #pragma unroll
  for (int ks = 0; ks < 8; ++ks)
    w2r[ks] = W2f[(ks * 8 + wave) * 64 + lane];

  float4 b1v[2];
  #pragma unroll
  for (int i = 0; i < 2; ++i)
    b1v[i] = *(const float4*)(b1 + (wave * 2 + i) * 16 + quad * 4);
  float4 b2v = *(const float4*)(b2 + wave * 16 + quad * 4);

  const int nTiles = NUM_M / TM;             // 3125 exact
  const int stride = gridDim.x;
  int tile = blockIdx.x;
  if (tile >= nTiles) return;
  int parity = 0;

  {
    #pragma unroll
    for (int k = 0; k < 4; ++k) {
      int2 p = fs[tile * TM + sr + k * 16];
      int e = shf ? p.y : p.x;
      bf16x8 v = *(const bf16x8*)(lsb + (size_t)e * DIM + si * 8);
      *(bf16x8*)&actL[0][swzm(sr + k * 16, shf * 128 + si * 8)] = v;
    }
  }
  int en[4] = {0, 0, 0, 0};
  {
    int t1 = tile + stride;
    if (t1 < nTiles) {
      #pragma unroll
      for (int k = 0; k < 4; ++k) {
        int2 p = fs[t1 * TM + sr + k * 16];
        en[k] = shf ? p.y : p.x;
      }
    }
  }
  __syncthreads();

  while (true) {
    const int m0 = tile * TM;
    const int next  = tile + stride;
    const int next2 = next + stride;
    const bool have_next  = (next < nTiles);   // block-uniform
    const bool have_next2 = (next2 < nTiles);

    bf16x8 sv[4];
    if (have_next) {
      #pragma unroll
      for (int k = 0; k < 4; ++k)
        sv[k] = *(const bf16x8*)(lsb + (size_t)en[k] * DIM + si * 8);
    }
    int2 p2[4];
    if (have_next2) {
      #pragma unroll
      for (int k = 0; k < 4; ++k)
        p2[k] = fs[next2 * TM + sr + k * 16];
    }

    const unsigned short* ab = &actL[parity][0];
    f32x4 acc[4][2];
    #pragma unroll
    for (int s = 0; s < 4; ++s) { acc[s][0] = (f32x4)(0.f); acc[s][1] = (f32x4)(0.f); }
    #pragma unroll
    for (int ks = 0; ks < 8; ++ks) {
      #pragma unroll
      for (int s = 0; s < 4; ++s) {
        bf16x8 b = *(const bf16x8*)&ab[swzm(s * 16 + c, ks * 32 + quad * 8)];
        acc[s][0] = MFMA(w1r[ks * 2 + 0], b, acc[s][0]);
        acc[s][1] = MFMA(w1r[ks * 2 + 1], b, acc[s][1]);
      }
    }

    if (have_next2) {
      #pragma unroll
      for (int k = 0; k < 4; ++k)
        en[k] = shf ? p2[k].y : p2[k].x;
    }

    if (have_next) {
      unsigned short* aw = &actL[parity ^ 1][0];
      #pragma unroll
      for (int k = 0; k < 4; ++k)
        *(bf16x8*)&aw[swzm(sr + k * 16, shf * 128 + si * 8)] = sv[k];
    }

    unsigned short* hb = &h1s[parity][0];
    #pragma unroll
    for (int i = 0; i < 2; ++i) {
      int n0 = (wave * 2 + i) * 16 + quad * 4;
      #pragma unroll
      for (int s = 0; s < 4; ++s) {
        ushort4 pk;
        pk.x = f2bf(relu_(acc[s][i][0] + b1v[i].x));
        pk.y = f2bf(relu_(acc[s][i][1] + b1v[i].y));
        pk.z = f2bf(relu_(acc[s][i][2] + b1v[i].z));
        pk.w = f2bf(relu_(acc[s][i][3] + b1v[i].w));
        *(ushort4*)&hb[swzm(s * 16 + c, n0)] = pk;
      }
    }
    __syncthreads();                         // the ONLY barrier per tile

    f32x4 a2[4];
    #pragma unroll
    for (int s = 0; s < 4; ++s) a2[s] = (f32x4)(0.f);
    #pragma unroll
    for (int ks2 = 0; ks2 < 8; ++ks2) {
      #pragma unroll
      for (int s = 0; s < 4; ++s) {
        bf16x8 b = *(const bf16x8*)&hb[swzm(s * 16 + c, ks2 * 32 + quad * 8)];
        a2[s] = MFMA(w2r[ks2], b, a2[s]);
      }
    }

    {
      int n0 = wave * 16 + quad * 4;
      #pragma unroll
      for (int s = 0; s < 4; ++s) {
        ushort4 pk;
        pk.x = f2bf(relu_(a2[s][0] + b2v.x));
        pk.y = f2bf(relu_(a2[s][1] + b2v.y));
        pk.z = f2bf(relu_(a2[s][2] + b2v.z));
        pk.w = f2bf(relu_(a2[s][3] + b2v.w));
        *(ushort4*)(msgout + (size_t)(m0 + s * 16 + c) * DIM + n0) = pk;
      }
    }

    if (!have_next) break;
    tile = next;
    parity ^= 1;
  }
}

// ---------------- GRU helpers ----------------
__device__ __forceinline__ ushort4 gru_gate(
    f32x4 az, f32x4 ar, f32x4 axh, f32x4 ahh, ushort4 hraw,
    float4 bz0, float4 br0, float4 bh0, float4 bz1, float4 br1, float4 bh1) {
  float ho[4] = { bf2f(hraw.x), bf2f(hraw.y), bf2f(hraw.z), bf2f(hraw.w) };
  const float* paz  = (const float*)&az;  const float* par  = (const float*)&ar;
  const float* paxh = (const float*)&axh; const float* pahh = (const float*)&ahh;
  const float* pz0 = (const float*)&bz0; const float* pr0 = (const float*)&br0;
  const float* ph0 = (const float*)&bh0; const float* pz1 = (const float*)&bz1;
  const float* pr1 = (const float*)&br1; const float* ph1 = (const float*)&bh1;
  unsigned short o[4];
  #pragma unroll
  for (int j = 0; j < 4; ++j) {
    float z  = sigmoidf_(paz[j] + pz0[j] + pz1[j]);
    float r  = sigmoidf_(par[j] + pr0[j] + pr1[j]);
    float hc = tanhf_(paxh[j] + ph0[j] + r * (pahh[j] + ph1[j]));
    o[j] = f2bf(z * ho[j] + (1.f - z) * hc);
  }
  return make_ushort4(o[0], o[1], o[2], o[3]);
}

// ---------------- GRU: cross-tile pipelined, 32-edge tiles (R17/R20-proven) ----------------
__global__ __launch_bounds__(512, 2) void gru_kernel(
    const unsigned short* __restrict__ msgb,  // [M,128] bf16, permuted (CSR row order)
    const int* __restrict__ rowptr,           // [E+1]
    unsigned short* __restrict__ lsb,         // h bf16, in-place (the only master)
    const unsigned short* __restrict__ Wzrp,  // packed [8][16][64][8]
    const unsigned short* __restrict__ Wkhp,  // packed [4][8][64][8]
    const unsigned short* __restrict__ Wrhp,  // packed [4][8][64][8]
    const float* __restrict__ gb)             // [2][384]
{
  __shared__ unsigned short xfL[2][32 * 128];   // 16 KB ping-pong, swizzled
  __shared__ unsigned short hfL[2][32 * 128];   // 16 KB ping-pong, swizzled

  const int tid  = threadIdx.x;
  const int wave = tid >> 6;                 // 0..7  = output nf slice
  const int lane = tid & 63;
  const int c    = lane & 15;
  const int quad = lane >> 4;

  const bf16x8* Wzrf = (const bf16x8*)Wzrp;
  const bf16x8* Wkhf = (const bf16x8*)Wkhp;
  const bf16x8* Wrhf = (const bf16x8*)Wrhp;
  bf16x8 wz[8], wr[8];                       // K=256 each: 64 VGPR
  #pragma unroll
  for (int ks = 0; ks < 8; ++ks) {
    wz[ks] = Wzrf[(ks * 16 + wave) * 64 + lane];
    wr[ks] = Wzrf[(ks * 16 + 8 + wave) * 64 + lane];
  }
  bf16x8 wxh[4], whh[4];                     // K=128 each: 32 VGPR
  #pragma unroll
  for (int ks = 0; ks < 4; ++ks) {
    wxh[ks] = Wkhf[(ks * 8 + wave) * 64 + lane];
    whh[ks] = Wrhf[(ks * 8 + wave) * 64 + lane];
  }

  const float4* gbv = (const float4*)gb;
  const int q4 = wave * 4 + quad;
  const float4 b0z = gbv[q4],      b0r = gbv[32 + q4],  b0h = gbv[64 + q4];
  const float4 b1z = gbv[96 + q4], b1r = gbv[128 + q4], b1h = gbv[160 + q4];

  const int el = wave * 4 + (lane >> 4);     // local edge 0..31
  const int li = lane & 15;                  // 16B chunk 0..15

  const int nTiles = NUM_E / 32;             // 3125 exact
  const int stride = gridDim.x;
  int tile = blockIdx.x;
  if (tile >= nTiles) return;
  int par = 0;

  {
    const int e  = tile * 32 + el;
    const int rs = rowptr[e], re = rowptr[e + 1];
    float xs[8];
    #pragma unroll
    for (int j = 0; j < 8; ++j) xs[j] = 0.f;
    bf16x8 hrow = *(const bf16x8*)(lsb + (size_t)e * DIM + li * 8);
    for (int p0 = rs; p0 < re; p0 += 8) {
      const int pm = re - 1;
      bf16x8 tv[8];
      #pragma unroll
      for (int k = 0; k < 8; ++k)
        tv[k] = *(const bf16x8*)(msgb + (size_t)min(p0 + k, pm) * DIM + li * 8);
      #pragma unroll
      for (int k = 0; k < 8; ++k)
        if (p0 + k < re) acc8(xs, tv[k]);
    }
    bf16x8 xv;
    #pragma unroll
    for (int j = 0; j < 8; ++j) xv[j] = (short)f2bf(xs[j]);
    *(bf16x8*)&xfL[0][swzg(el, li * 8)] = xv;
    *(bf16x8*)&hfL[0][swzg(el, li * 8)] = hrow;
  }
  int rs1 = 0, re1 = 0;
  if (tile + stride < nTiles) {
    const int e1 = (tile + stride) * 32 + el;
    rs1 = rowptr[e1]; re1 = rowptr[e1 + 1];
  }
  __syncthreads();

  while (true) {
    const int nextT = tile + stride;
    const bool have_next  = (nextT < nTiles);           // block-uniform
    const bool have_next2 = (nextT + stride < nTiles);

    bf16x8 r0, r1, r2, r3, r4, r5, r6, r7, hrow;
    if (have_next) {
      const int e1 = nextT * 32 + el;
      const int pc = min(max(re1 - 1, rs1), NUM_M - 1); // clamp (deg may be 0)
      r0 = *(const bf16x8*)(msgb + (size_t)min(rs1 + 0, pc) * DIM + li * 8);
      r1 = *(const bf16x8*)(msgb + (size_t)min(rs1 + 1, pc) * DIM + li * 8);
      r2 = *(const bf16x8*)(msgb + (size_t)min(rs1 + 2, pc) * DIM + li * 8);
      r3 = *(const bf16x8*)(msgb + (size_t)min(rs1 + 3, pc) * DIM + li * 8);
      r4 = *(const bf16x8*)(msgb + (size_t)min(rs1 + 4, pc) * DIM + li * 8);
      r5 = *(const bf16x8*)(msgb + (size_t)min(rs1 + 5, pc) * DIM + li * 8);
      r6 = *(const bf16x8*)(msgb + (size_t)min(rs1 + 6, pc) * DIM + li * 8);
      r7 = *(const bf16x8*)(msgb + (size_t)min(rs1 + 7, pc) * DIM + li * 8);
      hrow = *(const bf16x8*)(lsb + (size_t)e1 * DIM + li * 8);
    }
    int rs2 = 0, re2 = 0;
    if (have_next2) {
      const int e2 = (nextT + stride) * 32 + el;
      rs2 = rowptr[e2]; re2 = rowptr[e2 + 1];
    }

    const unsigned short* xb = &xfL[par][0];
    const unsigned short* hb = &hfL[par][0];
    f32x4 zA = (f32x4)(0.f), zB = (f32x4)(0.f);
    f32x4 rA = (f32x4)(0.f), rB = (f32x4)(0.f);
    f32x4 xhA = (f32x4)(0.f), xhB = (f32x4)(0.f);
    f32x4 hhA = (f32x4)(0.f), hhB = (f32x4)(0.f);
    #pragma unroll
    for (int ks = 0; ks < 4; ++ks) {
      bf16x8 xA = *(const bf16x8*)&xb[swzg(c,      ks * 32 + quad * 8)];
      bf16x8 xB = *(const bf16x8*)&xb[swzg(16 + c, ks * 32 + quad * 8)];
      bf16x8 hA = *(const bf16x8*)&hb[swzg(c,      ks * 32 + quad * 8)];
      bf16x8 hB = *(const bf16x8*)&hb[swzg(16 + c, ks * 32 + quad * 8)];
      zA  = MFMA(wz[ks],     xA, zA);   zB  = MFMA(wz[ks],     xB, zB);
      rA  = MFMA(wr[ks],     xA, rA);   rB  = MFMA(wr[ks],     xB, rB);
      zA  = MFMA(wz[4 + ks], hA, zA);   zB  = MFMA(wz[4 + ks], hB, zB);
      rA  = MFMA(wr[4 + ks], hA, rA);   rB  = MFMA(wr[4 + ks], hB, rB);
      xhA = MFMA(wxh[ks],    xA, xhA);  xhB = MFMA(wxh[ks],    xB, xhB);
      hhA = MFMA(whh[ks],    hA, hhA);  hhB = MFMA(whh[ks],    hB, hhB);
    }
    {
      const int n0 = wave * 16 + quad * 4;
      ushort4 hrawA = *(const ushort4*)&hb[swzg(c,      n0)];
      ushort4 hrawB = *(const ushort4*)&hb[swzg(16 + c, n0)];
      ushort4 pkA = gru_gate(zA, rA, xhA, hhA, hrawA, b0z, b0r, b0h, b1z, b1r, b1h);
      ushort4 pkB = gru_gate(zB, rB, xhB, hhB, hrawB, b0z, b0r, b0h, b1z, b1r, b1h);
      *(ushort4*)(lsb + (size_t)(tile * 32 + c) * DIM + n0)      = pkA;
      *(ushort4*)(lsb + (size_t)(tile * 32 + 16 + c) * DIM + n0) = pkB;
    }

    if (have_next) {
      float xs[8];
      #pragma unroll
      for (int j = 0; j < 8; ++j) xs[j] = 0.f;
      if (rs1 + 0 < re1) acc8(xs, r0);
      if (rs1 + 1 < re1) acc8(xs, r1);
      if (rs1 + 2 < re1) acc8(xs, r2);
      if (rs1 + 3 < re1) acc8(xs, r3);
      if (rs1 + 4 < re1) acc8(xs, r4);
      if (rs1 + 5 < re1) acc8(xs, r5);
      if (rs1 + 6 < re1) acc8(xs, r6);
      if (rs1 + 7 < re1) acc8(xs, r7);
      for (int p0 = rs1 + 8; p0 < re1; p0 += 8) {       // P(deg>8) ~ 0.02%
        const int pm = re1 - 1;
        bf16x8 tv[8];
        #pragma unroll
        for (int k = 0; k < 8; ++k)
          tv[k] = *(const bf16x8*)(msgb + (size_t)min(p0 + k, pm) * DIM + li * 8);
        #pragma unroll
        for (int k = 0; k < 8; ++k)
          if (p0 + k < re1) acc8(xs, tv[k]);
      }
      bf16x8 xv;
      #pragma unroll
      for (int j = 0; j < 8; ++j) xv[j] = (short)f2bf(xs[j]);
      *(bf16x8*)&xfL[par ^ 1][swzg(el, li * 8)] = xv;
      *(bf16x8*)&hfL[par ^ 1][swzg(el, li * 8)] = hrow;
    }
    __syncthreads();                         // the ONLY barrier per tile
    if (!have_next) break;
    tile = nextT;
    par ^= 1;
    rs1 = rs2;
    re1 = re2;
  }
}

// ---------------- fused graph-sum + readout: one block per graph (R26) ----------
// gids sorted -> block g binary-searches its segment [s0,s1), sums locally in
// fp32 (8-wide clamped/masked batch loads, gru-proven pattern), then runs the
// 3-layer readout MLP. Kills gs atomics, gs buffer, gs zeroing, one launch.
__global__ __launch_bounds__(256) void gsum_readout_kernel(
    const unsigned short* __restrict__ lsb, const int* __restrict__ gids,
    const float* __restrict__ rW1, const float* __restrict__ rb1,
    const float* __restrict__ rW2, const float* __restrict__ rb2,
    const float* __restrict__ rW3, const float* __restrict__ rb3,
    float* __restrict__ out) {
  __shared__ float shg[DIM];
  __shared__ float sh1[HID];
  __shared__ float red[HID];
  const int g = blockIdx.x, tid = threadIdx.x;
  const int d = tid & 127, half = tid >> 7;

  int s0, s1;
  {
    int lo = 0, hi = NUM_E;
    while (lo < hi) { int mid = (lo + hi) >> 1; if (gids[mid] < g) lo = mid + 1; else hi = mid; }
    s0 = lo;
    hi = NUM_E;
    while (lo < hi) { int mid = (lo + hi) >> 1; if (gids[mid] < g + 1) lo = mid + 1; else hi = mid; }
    s1 = lo;
  }

  float acc = 0.f;
  for (int eb = s0 + half; eb < s1; eb += 16) {     // 8 per stream, stride 2
    const int pm = s1 - 1;
    unsigned short tv[8];
    #pragma unroll
    for (int k = 0; k < 8; ++k)
      tv[k] = lsb[(size_t)min(eb + 2 * k, pm) * DIM + d];
    #pragma unroll
    for (int k = 0; k < 8; ++k)
      if (eb + 2 * k < s1) acc += bf2f(tv[k]);
  }
  red[tid] = acc;
  __syncthreads();
  if (tid < DIM) shg[tid] = red[tid] + red[tid + DIM];
  __syncthreads();
  float s = rb1[tid];
  for (int k = 0; k < DIM; ++k) s += shg[k] * rW1[k * HID + tid];
  sh1[tid] = relu_(s);
  __syncthreads();
  s = rb2[tid];
  for (int k = 0; k < HID; ++k) s += sh1[k] * rW2[k * HID + tid];
  red[tid] = relu_(s) * rW3[tid];
  __syncthreads();
  for (int off = 128; off > 0; off >>= 1) {
    if (tid < off) red[tid] += red[tid + off];
    __syncthreads();
  }
  if (tid == 0) out[g] = red[0] + rb3[0];
}

extern "C" void kernel_launch(void* const* d_in, const int* in_sizes, int n_in,
                              void* d_out, int out_size, void* d_ws, size_t ws_size,
                              hipStream_t stream) {
  float* ls          = (float*)d_in[0];        // fp32 link_state (read-only here)
  const int* first   = (const int*)d_in[1];
  const int* second  = (const int*)d_in[2];
  const int* gids    = (const int*)d_in[3];
  const float* mW1   = (const float*)d_in[5];
  const float* mb1   = (const float*)d_in[6];
  const float* mW2   = (const float*)d_in[7];
  const float* mb2   = (const float*)d_in[8];
  const float* gk    = (const float*)d_in[9];
  const float* gr    = (const float*)d_in[10];
  const float* gb    = (const float*)d_in[11];
  const float* rW1   = (const float*)d_in[12];
  const float* rb1   = (const float*)d_in[13];
  const float* rW2   = (const float*)d_in[14];
  const float* rb2   = (const float*)d_in[15];
  const float* rW3   = (const float*)d_in[16];
  const float* rb3   = (const float*)d_in[17];
  float* out = (float*)d_out;

  // workspace layout
  char* w = (char*)d_ws;
  unsigned short* msgb = (unsigned short*)w;    w += (size_t)NUM_M * DIM * 2;   // 51.2 MB
  unsigned short* lsb  = (unsigned short*)w;    w += (size_t)NUM_E * DIM * 2;   // 25.6 MB
  int* counts  = (int*)w;                       w += NUM_E * 4;
  int* cursor  = (int*)w;                       w += NUM_E * 4;   // adjacent to counts
  int* rowptr  = (int*)w;                       w += (NUM_E + 4) * 4;
  int2* fs     = (int2*)w;                      w += (size_t)NUM_M * 8;
  int* partials= (int*)w;                       w += NB_SCAN * 4;
  int* basep   = (int*)w;                       w += NB_SCAN * 4;
  unsigned short* W1p  = (unsigned short*)w;    w += 256 * 256 * 2;
  unsigned short* W2p  = (unsigned short*)w;    w += 256 * 128 * 2;
  unsigned short* Wzrp = (unsigned short*)w;    w += 256 * 256 * 2;
  unsigned short* Wkhp = (unsigned short*)w;    w += 128 * 128 * 2;
  unsigned short* Wrhp = (unsigned short*)w;    w += 128 * 128 * 2;

  // memset FIRST (counts + cursor), then fused prep (+hist)
  hipMemsetAsync(counts, 0, 2 * (size_t)NUM_E * 4, stream);
  const int n4 = NUM_E * DIM / 4;
  prep_kernel<<<(n4 + 255) / 256, 256, 0, stream>>>(
      (const float4*)ls, (ushort4*)lsb, n4, second, counts,
      mW1, mW2, gk, gr, W1p, W2p, Wzrp, Wkhp, Wrhp);

  // CSR build (parallel 3-kernel scan + packed-pair scatter)
  scan1_kernel<<<NB_SCAN, 256, 0, stream>>>(counts, partials);
  scan2_kernel<<<1, 64, 0, stream>>>(partials, basep, rowptr);
  scan3_kernel<<<NB_SCAN, 256, 0, stream>>>(counts, basep, rowptr);
  scatter_kernel<<<(NUM_M + 255) / 256, 256, 0, stream>>>(first, second, rowptr, cursor, fs);

  for (int t = 0; t < TITER; ++t) {
    msg_kernel<<<256, 512, 0, stream>>>(lsb, fs, W1p, mb1, W2p, mb2, msgb);
    gru_kernel<<<256, 512, 0, stream>>>(msgb, rowptr, lsb, Wzrp, Wkhp, Wrhp, gb);
  }
  gsum_readout_kernel<<<NG, HID, 0, stream>>>(lsb, gids, rW1, rb1, rW2, rb2, rW3, rb3, out);
}

// Round 16
// 491.511 us; speedup vs baseline: 1.2010x; 1.2010x over previous
//
#include <hip/hip_runtime.h>

#define NUM_E 100000
#define NUM_M 200000
#define DIM   128
#define HID   256
#define NG    64
#define TITER 3
#define NB_SCAN 98   // ceil(NUM_E/1024)
#define GS_ER 128    // edges per block in graph_sum
#define TM    64     // msg rows per tile (R21-proven)

typedef __attribute__((ext_vector_type(8))) short bf16x8;
typedef __attribute__((ext_vector_type(4))) float f32x4;

__device__ __forceinline__ unsigned short f2bf(float f) {
  unsigned u = __float_as_uint(f);
  u += 0x7FFF + ((u >> 16) & 1);          // RNE
  return (unsigned short)(u >> 16);
}
__device__ __forceinline__ float bf2f(unsigned short h) {
  return __uint_as_float(((unsigned)h) << 16);
}
__device__ __forceinline__ float sigmoidf_(float v) {
  return 1.f / (1.f + __expf(-v));
}
__device__ __forceinline__ float tanhf_(float u) {
  u = fminf(fmaxf(u, -15.f), 15.f);
  float ex = __expf(-2.f * u);
  return (1.f - ex) / (1.f + ex);
}
__device__ __forceinline__ float relu_(float v) { return fmaxf(v, 0.f); }

__device__ __forceinline__ void acc8(float* xs, bf16x8 v) {
  #pragma unroll
  for (int j = 0; j < 8; ++j) xs[j] += bf2f((unsigned short)v[j]);
}

// T2 XOR-swizzle (R20; neutral-to-positive, removes pad).
__device__ __forceinline__ int swzm(int row, int col) {   // msg: 256-ushort rows
  return row * 256 + (col ^ ((row & 7) << 3));
}
__device__ __forceinline__ int swzg(int row, int col) {   // gru: 128-ushort rows
  return row * 128 + (col ^ ((row & 7) << 3));
}

#define MFMA(a, b, c) __builtin_amdgcn_mfma_f32_16x16x32_bf16((a), (b), (c), 0, 0, 0)

// ---------------- 3-kernel parallel scan (coalesced; R10-proven) ----------------
__global__ __launch_bounds__(256) void scan1_kernel(const int* __restrict__ counts,
                                                    int* __restrict__ partials) {
  __shared__ int sh[256];
  int b = blockIdx.x, t = threadIdx.x;
  int i0 = b * 1024 + t * 4;
  int c0 = (i0 + 0 < NUM_E) ? counts[i0 + 0] : 0;
  int c1 = (i0 + 1 < NUM_E) ? counts[i0 + 1] : 0;
  int c2 = (i0 + 2 < NUM_E) ? counts[i0 + 2] : 0;
  int c3 = (i0 + 3 < NUM_E) ? counts[i0 + 3] : 0;
  int tsum = c0 + c1 + c2 + c3;
  sh[t] = tsum;
  __syncthreads();
  for (int off = 1; off < 256; off <<= 1) {
    int v = (t >= off) ? sh[t - off] : 0;
    __syncthreads();
    sh[t] += v;
    __syncthreads();
  }
  if (t == 255) partials[b] = sh[255];
}

__global__ void scan2_kernel(const int* __restrict__ partials, int* __restrict__ base,
                             int* __restrict__ rowptr) {
  if (threadIdx.x == 0) {
    int run = 0;
    for (int b = 0; b < NB_SCAN; ++b) { base[b] = run; run += partials[b]; }
    rowptr[NUM_E] = NUM_M;
  }
}

__global__ __launch_bounds__(256) void scan3_kernel(const int* __restrict__ counts,
                                                    const int* __restrict__ base,
                                                    int* __restrict__ rowptr) {
  __shared__ int sh[256];
  int b = blockIdx.x, t = threadIdx.x;
  int i0 = b * 1024 + t * 4;
  int c0 = (i0 + 0 < NUM_E) ? counts[i0 + 0] : 0;
  int c1 = (i0 + 1 < NUM_E) ? counts[i0 + 1] : 0;
  int c2 = (i0 + 2 < NUM_E) ? counts[i0 + 2] : 0;
  int c3 = (i0 + 3 < NUM_E) ? counts[i0 + 3] : 0;
  int tsum = c0 + c1 + c2 + c3;
  sh[t] = tsum;
  __syncthreads();
  for (int off = 1; off < 256; off <<= 1) {
    int v = (t >= off) ? sh[t - off] : 0;
    __syncthreads();
    sh[t] += v;
    __syncthreads();
  }
  int p = base[b] + (sh[t] - tsum);
  if (i0 + 0 < NUM_E) rowptr[i0 + 0] = p;
  if (i0 + 1 < NUM_E) rowptr[i0 + 1] = p + c0;
  if (i0 + 2 < NUM_E) rowptr[i0 + 2] = p + c0 + c1;
  if (i0 + 3 < NUM_E) rowptr[i0 + 3] = p + c0 + c1 + c2;
}

__global__ void scatter_kernel(const int* __restrict__ second,
                               const int* __restrict__ rowptr,
                               int* __restrict__ cursor, int* __restrict__ order) {
  int m = blockIdx.x * blockDim.x + threadIdx.x;
  if (m < NUM_M) {
    int e = second[m];
    int pos = atomicAdd(&cursor[e], 1);
    int idx = rowptr[e] + pos;
    if (idx < rowptr[e + 1]) order[idx] = m;   // guard: rocprof replay re-runs w/o re-zero
  }
}

// ---------------- fused prep: bf16 cvt + weight packs + HIST ----------------
__device__ __forceinline__ void pack_range(
    const float* __restrict__ srcA, const float* __restrict__ srcB, int KrowsA,
    int N, int src_ld, int col_off, unsigned short* __restrict__ dst, int idx) {
  int l = idx & 63;
  int t = idx >> 6;
  int NF = N / 16;
  int nf = t % NF;
  int ks = t / NF;
  int n = nf * 16 + (l & 15) + col_off;
  int k0 = ks * 32 + (l >> 4) * 8;
  unsigned short o[8];
  #pragma unroll
  for (int j = 0; j < 8; ++j) {
    int k = k0 + j;
    const float* src = (k < KrowsA) ? (srcA + (size_t)k * src_ld)
                                    : (srcB + (size_t)(k - KrowsA) * src_ld);
    o[j] = f2bf(src[n]);
  }
  ushort4* d = (ushort4*)(dst + (size_t)idx * 8);
  d[0] = make_ushort4(o[0], o[1], o[2], o[3]);
  d[1] = make_ushort4(o[4], o[5], o[6], o[7]);
}

// grid covers n4 = NUM_E*DIM/4 threads; first NUM_M also do the CSR histogram
// (counts memset'd BEFORE this launch); ids < 24576 also pack weights.
__global__ __launch_bounds__(256) void prep_kernel(
    const float4* __restrict__ ls4, ushort4* __restrict__ lsb4, int n4,
    const int* __restrict__ second, int* __restrict__ counts,
    float4* __restrict__ gs4,
    const float* __restrict__ mW1, const float* __restrict__ mW2,
    const float* __restrict__ gk,  const float* __restrict__ gr,
    unsigned short* __restrict__ W1p,  unsigned short* __restrict__ W2p,
    unsigned short* __restrict__ Wzrp, unsigned short* __restrict__ Wkhp,
    unsigned short* __restrict__ Wrhp) {
  int i = blockIdx.x * 256 + threadIdx.x;
  if (i < n4) {
    float4 v = ls4[i];
    ushort4 o;
    o.x = f2bf(v.x); o.y = f2bf(v.y); o.z = f2bf(v.z); o.w = f2bf(v.w);
    lsb4[i] = o;
  }
  if (i < NUM_M) atomicAdd(&counts[second[i]], 1);
  if (i < NG * DIM / 4) gs4[i] = make_float4(0.f, 0.f, 0.f, 0.f);
  if      (i < 8192)  pack_range(mW1, mW1, 256, 256, 256, 0,   W1p,  i);
  else if (i < 12288) pack_range(mW2, mW2, 256, 128, 128, 0,   W2p,  i - 8192);
  else if (i < 20480) pack_range(gk,  gr,  128, 256, 384, 0,   Wzrp, i - 12288);
  else if (i < 22528) pack_range(gk,  gk,  128, 128, 384, 256, Wkhp, i - 20480);
  else if (i < 24576) pack_range(gr,  gr,  128, 128, 384, 256, Wrhp, i - 22528);
}

// ---------------- message MLP: 64-row tiles (R21/R25-proven) ----------------
// R26 post-mortem: packing (first,second) into int2 added ~4 live staged regs
// -> compiler LDS-spilled (LDS 131072->147456, MfmaUtil 24->17, +47% dur).
// This kernel sits AT a register cliff; R25 form restored exactly.
__global__ __launch_bounds__(512, 2) void msg_kernel(
    const unsigned short* __restrict__ lsb,   // [E,128] bf16
    const int* __restrict__ first, const int* __restrict__ second,
    const int* __restrict__ order,            // [M] permutation
    const unsigned short* __restrict__ W1p,   // packed [8 ks][16 nf][64][8]
    const float* __restrict__ b1,
    const unsigned short* __restrict__ W2p,   // packed [8 ks][8 nf][64][8]
    const float* __restrict__ b2,
    unsigned short* __restrict__ msgout)
{
  __shared__ unsigned short actL[2][TM * 256];   // 2 x 32 KB, swizzled
  __shared__ unsigned short h1s[2][TM * 256];    // 2 x 32 KB, swizzled

  const int tid  = threadIdx.x;
  const int wave = tid >> 6;                 // 0..7
  const int lane = tid & 63;
  const int c    = lane & 15;
  const int quad = lane >> 4;

  const int sr  = tid >> 5;                  // 0..15
  const int shf = (tid >> 4) & 1;            // 0 = main(first), 1 = neigh(second)
  const int si  = tid & 15;                  // 16B chunk index

  const bf16x8* W1f = (const bf16x8*)W1p;
  const bf16x8* W2f = (const bf16x8*)W2p;
  bf16x8 w1r[16];                            // 64 VGPR
  #pragma unroll
  for (int ks = 0; ks < 8; ++ks)
    #pragma unroll
    for (int i = 0; i < 2; ++i)
      w1r[ks * 2 + i] = W1f[(ks * 16 + wave * 2 + i) * 64 + lane];
  bf16x8 w2r[8];                             // 32 VGPR
  #pragma unroll
  for (int ks = 0; ks < 8; ++ks)
    w2r[ks] = W2f[(ks * 8 + wave) * 64 + lane];

  float4 b1v[2];
  #pragma unroll
  for (int i = 0; i < 2; ++i)
    b1v[i] = *(const float4*)(b1 + (wave * 2 + i) * 16 + quad * 4);
  float4 b2v = *(const float4*)(b2 + wave * 16 + quad * 4);

  const int nTiles = NUM_M / TM;             // 3125 exact
  const int stride = gridDim.x;
  int tile = blockIdx.x;
  if (tile >= nTiles) return;
  int parity = 0;

  {
    #pragma unroll
    for (int k = 0; k < 4; ++k) {
      int m = order[tile * TM + sr + k * 16];
      int e = shf ? second[m] : first[m];
      bf16x8 v = *(const bf16x8*)(lsb + (size_t)e * DIM + si * 8);
      *(bf16x8*)&actL[0][swzm(sr + k * 16, shf * 128 + si * 8)] = v;
    }
  }
  int en[4] = {0, 0, 0, 0};
  {
    int t1 = tile + stride;
    if (t1 < nTiles) {
      #pragma unroll
      for (int k = 0; k < 4; ++k) {
        int m = order[t1 * TM + sr + k * 16];
        en[k] = shf ? second[m] : first[m];
      }
    }
  }
  __syncthreads();

  while (true) {
    const int m0 = tile * TM;
    const int next  = tile + stride;
    const int next2 = next + stride;
    const bool have_next  = (next < nTiles);   // block-uniform
    const bool have_next2 = (next2 < nTiles);

    bf16x8 sv[4];
    if (have_next) {
      #pragma unroll
      for (int k = 0; k < 4; ++k)
        sv[k] = *(const bf16x8*)(lsb + (size_t)en[k] * DIM + si * 8);
    }
    int o[4] = {0, 0, 0, 0};
    if (have_next2) {
      #pragma unroll
      for (int k = 0; k < 4; ++k)
        o[k] = order[next2 * TM + sr + k * 16];
    }

    const unsigned short* ab = &actL[parity][0];
    f32x4 acc[4][2];
    #pragma unroll
    for (int s = 0; s < 4; ++s) { acc[s][0] = (f32x4)(0.f); acc[s][1] = (f32x4)(0.f); }
    #pragma unroll
    for (int ks = 0; ks < 8; ++ks) {
      #pragma unroll
      for (int s = 0; s < 4; ++s) {
        bf16x8 b = *(const bf16x8*)&ab[swzm(s * 16 + c, ks * 32 + quad * 8)];
        acc[s][0] = MFMA(w1r[ks * 2 + 0], b, acc[s][0]);
        acc[s][1] = MFMA(w1r[ks * 2 + 1], b, acc[s][1]);
      }
    }

    if (have_next2) {
      #pragma unroll
      for (int k = 0; k < 4; ++k)
        en[k] = shf ? second[o[k]] : first[o[k]];
    }

    if (have_next) {
      unsigned short* aw = &actL[parity ^ 1][0];
      #pragma unroll
      for (int k = 0; k < 4; ++k)
        *(bf16x8*)&aw[swzm(sr + k * 16, shf * 128 + si * 8)] = sv[k];
    }

    unsigned short* hb = &h1s[parity][0];
    #pragma unroll
    for (int i = 0; i < 2; ++i) {
      int n0 = (wave * 2 + i) * 16 + quad * 4;
      #pragma unroll
      for (int s = 0; s < 4; ++s) {
        ushort4 pk;
        pk.x = f2bf(relu_(acc[s][i][0] + b1v[i].x));
        pk.y = f2bf(relu_(acc[s][i][1] + b1v[i].y));
        pk.z = f2bf(relu_(acc[s][i][2] + b1v[i].z));
        pk.w = f2bf(relu_(acc[s][i][3] + b1v[i].w));
        *(ushort4*)&hb[swzm(s * 16 + c, n0)] = pk;
      }
    }
    __syncthreads();                         // the ONLY barrier per tile

    f32x4 a2[4];
    #pragma unroll
    for (int s = 0; s < 4; ++s) a2[s] = (f32x4)(0.f);
    #pragma unroll
    for (int ks2 = 0; ks2 < 8; ++ks2) {
      #pragma unroll
      for (int s = 0; s < 4; ++s) {
        bf16x8 b = *(const bf16x8*)&hb[swzm(s * 16 + c, ks2 * 32 + quad * 8)];
        a2[s] = MFMA(w2r[ks2], b, a2[s]);
      }
    }

    {
      int n0 = wave * 16 + quad * 4;
      #pragma unroll
      for (int s = 0; s < 4; ++s) {
        ushort4 pk;
        pk.x = f2bf(relu_(a2[s][0] + b2v.x));
        pk.y = f2bf(relu_(a2[s][1] + b2v.y));
        pk.z = f2bf(relu_(a2[s][2] + b2v.z));
        pk.w = f2bf(relu_(a2[s][3] + b2v.w));
        *(ushort4*)(msgout + (size_t)(m0 + s * 16 + c) * DIM + n0) = pk;
      }
    }

    if (!have_next) break;
    tile = next;
    parity ^= 1;
  }
}

// ---------------- GRU helpers ----------------
__device__ __forceinline__ ushort4 gru_gate(
    f32x4 az, f32x4 ar, f32x4 axh, f32x4 ahh, ushort4 hraw,
    float4 bz0, float4 br0, float4 bh0, float4 bz1, float4 br1, float4 bh1) {
  float ho[4] = { bf2f(hraw.x), bf2f(hraw.y), bf2f(hraw.z), bf2f(hraw.w) };
  const float* paz  = (const float*)&az;  const float* par  = (const float*)&ar;
  const float* paxh = (const float*)&axh; const float* pahh = (const float*)&ahh;
  const float* pz0 = (const float*)&bz0; const float* pr0 = (const float*)&br0;
  const float* ph0 = (const float*)&bh0; const float* pz1 = (const float*)&bz1;
  const float* pr1 = (const float*)&br1; const float* ph1 = (const float*)&bh1;
  unsigned short o[4];
  #pragma unroll
  for (int j = 0; j < 4; ++j) {
    float z  = sigmoidf_(paz[j] + pz0[j] + pz1[j]);
    float r  = sigmoidf_(par[j] + pr0[j] + pr1[j]);
    float hc = tanhf_(paxh[j] + ph0[j] + r * (pahh[j] + ph1[j]));
    o[j] = f2bf(z * ho[j] + (1.f - z) * hc);
  }
  return make_ushort4(o[0], o[1], o[2], o[3]);
}

// ---------------- GRU: cross-tile pipelined, 32-edge tiles (R17/R20-proven) ----------------
__global__ __launch_bounds__(512, 2) void gru_kernel(
    const unsigned short* __restrict__ msgb,  // [M,128] bf16, permuted (CSR row order)
    const int* __restrict__ rowptr,           // [E+1]
    unsigned short* __restrict__ lsb,         // h bf16, in-place (the only master)
    const unsigned short* __restrict__ Wzrp,  // packed [8][16][64][8]
    const unsigned short* __restrict__ Wkhp,  // packed [4][8][64][8]
    const unsigned short* __restrict__ Wrhp,  // packed [4][8][64][8]
    const float* __restrict__ gb)             // [2][384]
{
  __shared__ unsigned short xfL[2][32 * 128];   // 16 KB ping-pong, swizzled
  __shared__ unsigned short hfL[2][32 * 128];   // 16 KB ping-pong, swizzled

  const int tid  = threadIdx.x;
  const int wave = tid >> 6;                 // 0..7  = output nf slice
  const int lane = tid & 63;
  const int c    = lane & 15;
  const int quad = lane >> 4;

  const bf16x8* Wzrf = (const bf16x8*)Wzrp;
  const bf16x8* Wkhf = (const bf16x8*)Wkhp;
  const bf16x8* Wrhf = (const bf16x8*)Wrhp;
  bf16x8 wz[8], wr[8];                       // K=256 each: 64 VGPR
  #pragma unroll
  for (int ks = 0; ks < 8; ++ks) {
    wz[ks] = Wzrf[(ks * 16 + wave) * 64 + lane];
    wr[ks] = Wzrf[(ks * 16 + 8 + wave) * 64 + lane];
  }
  bf16x8 wxh[4], whh[4];                     // K=128 each: 32 VGPR
  #pragma unroll
  for (int ks = 0; ks < 4; ++ks) {
    wxh[ks] = Wkhf[(ks * 8 + wave) * 64 + lane];
    whh[ks] = Wrhf[(ks * 8 + wave) * 64 + lane];
  }

  const float4* gbv = (const float4*)gb;
  const int q4 = wave * 4 + quad;
  const float4 b0z = gbv[q4],      b0r = gbv[32 + q4],  b0h = gbv[64 + q4];
  const float4 b1z = gbv[96 + q4], b1r = gbv[128 + q4], b1h = gbv[160 + q4];

  const int el = wave * 4 + (lane >> 4);     // local edge 0..31
  const int li = lane & 15;                  // 16B chunk 0..15

  const int nTiles = NUM_E / 32;             // 3125 exact
  const int stride = gridDim.x;
  int tile = blockIdx.x;
  if (tile >= nTiles) return;
  int par = 0;

  {
    const int e  = tile * 32 + el;
    const int rs = rowptr[e], re = rowptr[e + 1];
    float xs[8];
    #pragma unroll
    for (int j = 0; j < 8; ++j) xs[j] = 0.f;
    bf16x8 hrow = *(const bf16x8*)(lsb + (size_t)e * DIM + li * 8);
    for (int p0 = rs; p0 < re; p0 += 8) {
      const int pm = re - 1;
      bf16x8 tv[8];
      #pragma unroll
      for (int k = 0; k < 8; ++k)
        tv[k] = *(const bf16x8*)(msgb + (size_t)min(p0 + k, pm) * DIM + li * 8);
      #pragma unroll
      for (int k = 0; k < 8; ++k)
        if (p0 + k < re) acc8(xs, tv[k]);
    }
    bf16x8 xv;
    #pragma unroll
    for (int j = 0; j < 8; ++j) xv[j] = (short)f2bf(xs[j]);
    *(bf16x8*)&xfL[0][swzg(el, li * 8)] = xv;
    *(bf16x8*)&hfL[0][swzg(el, li * 8)] = hrow;
  }
  int rs1 = 0, re1 = 0;
  if (tile + stride < nTiles) {
    const int e1 = (tile + stride) * 32 + el;
    rs1 = rowptr[e1]; re1 = rowptr[e1 + 1];
  }
  __syncthreads();

  while (true) {
    const int nextT = tile + stride;
    const bool have_next  = (nextT < nTiles);           // block-uniform
    const bool have_next2 = (nextT + stride < nTiles);

    bf16x8 r0, r1, r2, r3, r4, r5, r6, r7, hrow;
    if (have_next) {
      const int e1 = nextT * 32 + el;
      const int pc = min(max(re1 - 1, rs1), NUM_M - 1); // clamp (deg may be 0)
      r0 = *(const bf16x8*)(msgb + (size_t)min(rs1 + 0, pc) * DIM + li * 8);
      r1 = *(const bf16x8*)(msgb + (size_t)min(rs1 + 1, pc) * DIM + li * 8);
      r2 = *(const bf16x8*)(msgb + (size_t)min(rs1 + 2, pc) * DIM + li * 8);
      r3 = *(const bf16x8*)(msgb + (size_t)min(rs1 + 3, pc) * DIM + li * 8);
      r4 = *(const bf16x8*)(msgb + (size_t)min(rs1 + 4, pc) * DIM + li * 8);
      r5 = *(const bf16x8*)(msgb + (size_t)min(rs1 + 5, pc) * DIM + li * 8);
      r6 = *(const bf16x8*)(msgb + (size_t)min(rs1 + 6, pc) * DIM + li * 8);
      r7 = *(const bf16x8*)(msgb + (size_t)min(rs1 + 7, pc) * DIM + li * 8);
      hrow = *(const bf16x8*)(lsb + (size_t)e1 * DIM + li * 8);
    }
    int rs2 = 0, re2 = 0;
    if (have_next2) {
      const int e2 = (nextT + stride) * 32 + el;
      rs2 = rowptr[e2]; re2 = rowptr[e2 + 1];
    }

    const unsigned short* xb = &xfL[par][0];
    const unsigned short* hb = &hfL[par][0];
    f32x4 zA = (f32x4)(0.f), zB = (f32x4)(0.f);
    f32x4 rA = (f32x4)(0.f), rB = (f32x4)(0.f);
    f32x4 xhA = (f32x4)(0.f), xhB = (f32x4)(0.f);
    f32x4 hhA = (f32x4)(0.f), hhB = (f32x4)(0.f);
    #pragma unroll
    for (int ks = 0; ks < 4; ++ks) {
      bf16x8 xA = *(const bf16x8*)&xb[swzg(c,      ks * 32 + quad * 8)];
      bf16x8 xB = *(const bf16x8*)&xb[swzg(16 + c, ks * 32 + quad * 8)];
      bf16x8 hA = *(const bf16x8*)&hb[swzg(c,      ks * 32 + quad * 8)];
      bf16x8 hB = *(const bf16x8*)&hb[swzg(16 + c, ks * 32 + quad * 8)];
      zA  = MFMA(wz[ks],     xA, zA);   zB  = MFMA(wz[ks],     xB, zB);
      rA  = MFMA(wr[ks],     xA, rA);   rB  = MFMA(wr[ks],     xB, rB);
      zA  = MFMA(wz[4 + ks], hA, zA);   zB  = MFMA(wz[4 + ks], hB, zB);
      rA  = MFMA(wr[4 + ks], hA, rA);   rB  = MFMA(wr[4 + ks], hB, rB);
      xhA = MFMA(wxh[ks],    xA, xhA);  xhB = MFMA(wxh[ks],    xB, xhB);
      hhA = MFMA(whh[ks],    hA, hhA);  hhB = MFMA(whh[ks],    hB, hhB);
    }
    {
      const int n0 = wave * 16 + quad * 4;
      ushort4 hrawA = *(const ushort4*)&hb[swzg(c,      n0)];
      ushort4 hrawB = *(const ushort4*)&hb[swzg(16 + c, n0)];
      ushort4 pkA = gru_gate(zA, rA, xhA, hhA, hrawA, b0z, b0r, b0h, b1z, b1r, b1h);
      ushort4 pkB = gru_gate(zB, rB, xhB, hhB, hrawB, b0z, b0r, b0h, b1z, b1r, b1h);
      *(ushort4*)(lsb + (size_t)(tile * 32 + c) * DIM + n0)      = pkA;
      *(ushort4*)(lsb + (size_t)(tile * 32 + 16 + c) * DIM + n0) = pkB;
    }

    if (have_next) {
      float xs[8];
      #pragma unroll
      for (int j = 0; j < 8; ++j) xs[j] = 0.f;
      if (rs1 + 0 < re1) acc8(xs, r0);
      if (rs1 + 1 < re1) acc8(xs, r1);
      if (rs1 + 2 < re1) acc8(xs, r2);
      if (rs1 + 3 < re1) acc8(xs, r3);
      if (rs1 + 4 < re1) acc8(xs, r4);
      if (rs1 + 5 < re1) acc8(xs, r5);
      if (rs1 + 6 < re1) acc8(xs, r6);
      if (rs1 + 7 < re1) acc8(xs, r7);
      for (int p0 = rs1 + 8; p0 < re1; p0 += 8) {       // P(deg>8) ~ 0.02%
        const int pm = re1 - 1;
        bf16x8 tv[8];
        #pragma unroll
        for (int k = 0; k < 8; ++k)
          tv[k] = *(const bf16x8*)(msgb + (size_t)min(p0 + k, pm) * DIM + li * 8);
        #pragma unroll
        for (int k = 0; k < 8; ++k)
          if (p0 + k < re1) acc8(xs, tv[k]);
      }
      bf16x8 xv;
      #pragma unroll
      for (int j = 0; j < 8; ++j) xv[j] = (short)f2bf(xs[j]);
      *(bf16x8*)&xfL[par ^ 1][swzg(el, li * 8)] = xv;
      *(bf16x8*)&hfL[par ^ 1][swzg(el, li * 8)] = hrow;
    }
    __syncthreads();                         // the ONLY barrier per tile
    if (!have_next) break;
    tile = nextT;
    par ^= 1;
    rs1 = rs2;
    re1 = re2;
  }
}

// ---------------- graph segment-sum (sorted ids; reads bf16 h, fp32 accum) ----------------
__global__ __launch_bounds__(256) void graph_sum_kernel(
    const unsigned short* __restrict__ lsb, const int* __restrict__ gids,
    float* __restrict__ gs) {
  const int t = threadIdx.x;
  const int d = t & 127;
  const int half = t >> 7;
  const int e0 = blockIdx.x * GS_ER;
  const int e1 = min(e0 + GS_ER, NUM_E);
  float acc = 0.f;
  int cur = -1;
  for (int e = e0 + half; e < e1; e += 2) {
    int g = gids[e];
    if (g != cur) {
      if (cur >= 0) atomicAdd(&gs[cur * DIM + d], acc);
      acc = 0.f;
      cur = g;
    }
    acc += bf2f(lsb[(size_t)e * DIM + d]);
  }
  if (cur >= 0) atomicAdd(&gs[cur * DIM + d], acc);
}

// ---------------- fused readout: 3 layers in one kernel ----------------
__global__ __launch_bounds__(256) void readout_kernel(
    const float* __restrict__ gs,
    const float* __restrict__ rW1, const float* __restrict__ rb1,
    const float* __restrict__ rW2, const float* __restrict__ rb2,
    const float* __restrict__ rW3, const float* __restrict__ rb3,
    float* __restrict__ out) {
  __shared__ float shg[DIM];
  __shared__ float sh1[HID];
  __shared__ float red[HID];
  int g = blockIdx.x, c = threadIdx.x;
  if (c < DIM) shg[c] = gs[g * DIM + c];
  __syncthreads();
  float s = rb1[c];
  for (int k = 0; k < DIM; ++k) s += shg[k] * rW1[k * HID + c];
  sh1[c] = relu_(s);
  __syncthreads();
  s = rb2[c];
  for (int k = 0; k < HID; ++k) s += sh1[k] * rW2[k * HID + c];
  red[c] = relu_(s) * rW3[c];
  __syncthreads();
  for (int off = 128; off > 0; off >>= 1) {
    if (c < off) red[c] += red[c + off];
    __syncthreads();
  }
  if (c == 0) out[g] = red[0] + rb3[0];
}

extern "C" void kernel_launch(void* const* d_in, const int* in_sizes, int n_in,
                              void* d_out, int out_size, void* d_ws, size_t ws_size,
                              hipStream_t stream) {
  float* ls          = (float*)d_in[0];        // fp32 link_state (read-only here)
  const int* first   = (const int*)d_in[1];
  const int* second  = (const int*)d_in[2];
  const int* gids    = (const int*)d_in[3];
  const float* mW1   = (const float*)d_in[5];
  const float* mb1   = (const float*)d_in[6];
  const float* mW2   = (const float*)d_in[7];
  const float* mb2   = (const float*)d_in[8];
  const float* gk    = (const float*)d_in[9];
  const float* gr    = (const float*)d_in[10];
  const float* gb    = (const float*)d_in[11];
  const float* rW1   = (const float*)d_in[12];
  const float* rb1   = (const float*)d_in[13];
  const float* rW2   = (const float*)d_in[14];
  const float* rb2   = (const float*)d_in[15];
  const float* rW3   = (const float*)d_in[16];
  const float* rb3   = (const float*)d_in[17];
  float* out = (float*)d_out;

  // workspace layout
  char* w = (char*)d_ws;
  unsigned short* msgb = (unsigned short*)w;    w += (size_t)NUM_M * DIM * 2;   // 51.2 MB
  unsigned short* lsb  = (unsigned short*)w;    w += (size_t)NUM_E * DIM * 2;   // 25.6 MB
  float* gs    = (float*)w;                     w += NG * DIM * 4;
  int* counts  = (int*)w;                       w += NUM_E * 4;
  int* cursor  = (int*)w;                       w += NUM_E * 4;   // adjacent to counts
  int* rowptr  = (int*)w;                       w += (NUM_E + 4) * 4;
  int* order   = (int*)w;                       w += NUM_M * 4;
  int* partials= (int*)w;                       w += NB_SCAN * 4;
  int* basep   = (int*)w;                       w += NB_SCAN * 4;
  unsigned short* W1p  = (unsigned short*)w;    w += 256 * 256 * 2;
  unsigned short* W2p  = (unsigned short*)w;    w += 256 * 128 * 2;
  unsigned short* Wzrp = (unsigned short*)w;    w += 256 * 256 * 2;
  unsigned short* Wkhp = (unsigned short*)w;    w += 128 * 128 * 2;
  unsigned short* Wrhp = (unsigned short*)w;    w += 128 * 128 * 2;

  // memset FIRST (counts + cursor), then fused prep (+hist +gs-zero)
  hipMemsetAsync(counts, 0, 2 * (size_t)NUM_E * 4, stream);
  const int n4 = NUM_E * DIM / 4;
  prep_kernel<<<(n4 + 255) / 256, 256, 0, stream>>>(
      (const float4*)ls, (ushort4*)lsb, n4, second, counts, (float4*)gs,
      mW1, mW2, gk, gr, W1p, W2p, Wzrp, Wkhp, Wrhp);

  // CSR build (parallel 3-kernel scan)
  scan1_kernel<<<NB_SCAN, 256, 0, stream>>>(counts, partials);
  scan2_kernel<<<1, 64, 0, stream>>>(partials, basep, rowptr);
  scan3_kernel<<<NB_SCAN, 256, 0, stream>>>(counts, basep, rowptr);
  scatter_kernel<<<(NUM_M + 255) / 256, 256, 0, stream>>>(second, rowptr, cursor, order);

  for (int t = 0; t < TITER; ++t) {
    msg_kernel<<<256, 512, 0, stream>>>(lsb, first, second, order, W1p, mb1, W2p, mb2, msgb);
    gru_kernel<<<256, 512, 0, stream>>>(msgb, rowptr, lsb, Wzrp, Wkhp, Wrhp, gb);
  }
  graph_sum_kernel<<<(NUM_E + GS_ER - 1) / GS_ER, 256, 0, stream>>>(lsb, gids, gs);
  readout_kernel<<<NG, HID, 0, stream>>>(gs, rW1, rb1, rW2, rb2, rW3, rb3, out);
}